// Round 5
// baseline (712.821 us; speedup 1.0000x reference)
//
#include <hip/hip_runtime.h>
#include <math.h>

#define B_ 8
#define N_ 1024
#define C_ 256
#define H_ 4
#define D_ 64
#define CN_ 256
#define EPS_ 1e-6f

// ---------------- threefry2x32 (JAX-compatible) ----------------
__device__ __forceinline__ unsigned rotl32(unsigned x, int r){ return (x<<r)|(x>>(32-r)); }

__device__ float tf_noise(unsigned gid){
  unsigned c0 = (gid >= 4096u) ? gid - 4096u : gid;
  unsigned c1 = c0 + 4096u;
  const unsigned k0 = 0u, k1 = 42u;
  const unsigned ks2 = k0 ^ k1 ^ 0x1BD11BDAu;
  unsigned x0 = c0 + k0, x1 = c1 + k1;
  const int R0[4] = {13,15,26,6};
  const int R1[4] = {17,29,16,24};
  #pragma unroll
  for (int i=0;i<4;i++){ x0 += x1; x1 = rotl32(x1,R0[i]); x1 ^= x0; }
  x0 += k1; x1 += ks2 + 1u;
  #pragma unroll
  for (int i=0;i<4;i++){ x0 += x1; x1 = rotl32(x1,R1[i]); x1 ^= x0; }
  x0 += ks2; x1 += k0 + 2u;
  #pragma unroll
  for (int i=0;i<4;i++){ x0 += x1; x1 = rotl32(x1,R0[i]); x1 ^= x0; }
  x0 += k0; x1 += k1 + 3u;
  #pragma unroll
  for (int i=0;i<4;i++){ x0 += x1; x1 = rotl32(x1,R1[i]); x1 ^= x0; }
  x0 += k1; x1 += ks2 + 4u;
  #pragma unroll
  for (int i=0;i<4;i++){ x0 += x1; x1 = rotl32(x1,R0[i]); x1 ^= x0; }
  x0 += ks2; x1 += k0 + 5u;
  unsigned bits = (gid >= 4096u) ? x1 : x0;
  return __uint_as_float(0x3F800000u | (bits >> 9)) - 1.0f;
}

// ---------------- sq of rows ----------------
__global__ __launch_bounds__(256) void k_sq(const float* __restrict__ x, float* __restrict__ sq){
  int row = blockIdx.x * 4 + (threadIdx.x >> 6);
  int l = threadIdx.x & 63;
  const float* p = x + (size_t)row * C_;
  float s = 0.f;
  #pragma unroll
  for (int t=0;t<4;t++){ float v = p[l + 64*t]; s += v*v; }
  #pragma unroll
  for (int m=32;m;m>>=1) s += __shfl_xor(s, m);
  if (l==0) sq[row] = s;
}

// 64-thread 64x64-tile GEMM core, register-pipelined.
#define GLOAD(RA, RB, PA, PB, K0)                                              \
  _Pragma("unroll")                                                            \
  for (int f=0; f<4; f++){                                                     \
    int e = f*64 + t; int row = e >> 2, kq = e & 3;                            \
    RA[f] = *(const float4*)(PA + (size_t)row*C_ + (K0) + kq*4);               \
    RB[f] = *(const float4*)(PB + (size_t)row*C_ + (K0) + kq*4);               \
  }

#define LWRITE(RA, RB)                                                         \
  _Pragma("unroll")                                                            \
  for (int f=0; f<4; f++){                                                     \
    int e = f*64 + t; int row = e >> 2, kq = e & 3;                            \
    As[kq*4+0][row]=RA[f].x; As[kq*4+1][row]=RA[f].y;                          \
    As[kq*4+2][row]=RA[f].z; As[kq*4+3][row]=RA[f].w;                          \
    Bs[kq*4+0][row]=RB[f].x; Bs[kq*4+1][row]=RB[f].y;                          \
    Bs[kq*4+2][row]=RB[f].z; Bs[kq*4+3][row]=RB[f].w;                          \
  }

#define INNER64                                                                \
  _Pragma("unroll")                                                            \
  for (int kk=0;kk<16;kk++){                                                   \
    float4 a0 = *(const float4*)&As[kk][ty*4];                                 \
    float4 a1 = *(const float4*)&As[kk][32+ty*4];                              \
    float4 b0 = *(const float4*)&Bs[kk][tx*4];                                 \
    float4 b1 = *(const float4*)&Bs[kk][32+tx*4];                              \
    float av[8]={a0.x,a0.y,a0.z,a0.w,a1.x,a1.y,a1.z,a1.w};                     \
    float bv[8]={b0.x,b0.y,b0.z,b0.w,b1.x,b1.y,b1.z,b1.w};                     \
    _Pragma("unroll")                                                          \
    for (int r=0;r<8;r++)                                                      \
      _Pragma("unroll")                                                        \
      for (int c=0;c<8;c++) acc[r][c] += av[r]*bv[c];                          \
  }

// pipelined K-loop: 2 slabs per iteration, reg ping-pong
#define KLOOP_PIPE                                                             \
  float4 rA0[4], rB0[4], rA1[4], rB1[4];                                       \
  GLOAD(rA0, rB0, pa, pb, 0)                                                   \
  for (int s2=0; s2<8; ++s2){                                                  \
    LWRITE(rA0, rB0)                                                           \
    __syncthreads();                                                           \
    GLOAD(rA1, rB1, pa, pb, s2*32+16)                                          \
    INNER64                                                                    \
    __syncthreads();                                                           \
    LWRITE(rA1, rB1)                                                           \
    __syncthreads();                                                           \
    if (s2<7){ GLOAD(rA0, rB0, pa, pb, s2*32+32) }                             \
    INNER64                                                                    \
    __syncthreads();                                                           \
  }

// ---------------- dist GEMM: symmetric pairs, 64x64 tiles, 1 wave/block ----------------
__global__ __launch_bounds__(64, 2) void k_dist3(const float* __restrict__ x, const float* __restrict__ sq,
                                                 float* __restrict__ dist){
  int b = blockIdx.y;
  int p = blockIdx.x;
  int bi = 0, rem = p;
  while (rem >= 16 - bi){ rem -= 16 - bi; bi++; }
  int bj = bi + rem;
  const float* xb = x + (size_t)b*N_*C_;
  const float* pa = xb + (size_t)(bi*64)*C_;
  const float* pb = xb + (size_t)(bj*64)*C_;
  __shared__ float As[16][68];
  __shared__ float Bs[16][68];
  int t = threadIdx.x;
  int tx = t & 7, ty = t >> 3;
  float acc[8][8] = {};
  KLOOP_PIPE
  float sqj[8];
  #pragma unroll
  for (int cc=0;cc<2;cc++)
    #pragma unroll
    for (int c=0;c<4;c++) sqj[cc*4+c] = sq[b*N_ + bj*64 + cc*32 + tx*4 + c];
  float o[8][8];
  #pragma unroll
  for (int rr=0;rr<2;rr++){
    #pragma unroll
    for (int r=0;r<4;r++){
      int i = bi*64 + rr*32 + ty*4 + r;
      float si = sq[b*N_ + i];
      #pragma unroll
      for (int cc=0;cc<2;cc++)
        #pragma unroll
        for (int c=0;c<4;c++){
          float d2 = si + sqj[cc*4+c] - 2.f*acc[rr*4+r][cc*4+c];
          o[rr*4+r][cc*4+c] = sqrtf(fmaxf(d2, 0.f)) * 0.0625f;
        }
    }
  }
  float* dbase = dist + (size_t)b*N_*N_;
  #pragma unroll
  for (int rr=0;rr<2;rr++)
    #pragma unroll
    for (int r=0;r<4;r++){
      int i = bi*64 + rr*32 + ty*4 + r;
      #pragma unroll
      for (int cc=0;cc<2;cc++){
        int j0 = bj*64 + cc*32 + tx*4;
        *(float4*)(dbase + (size_t)i*N_ + j0) =
          make_float4(o[rr*4+r][cc*4+0], o[rr*4+r][cc*4+1], o[rr*4+r][cc*4+2], o[rr*4+r][cc*4+3]);
      }
    }
  if (bi != bj){
    #pragma unroll
    for (int cc=0;cc<2;cc++)
      #pragma unroll
      for (int c=0;c<4;c++){
        int j = bj*64 + cc*32 + tx*4 + c;
        #pragma unroll
        for (int rr=0;rr<2;rr++){
          int i0 = bi*64 + rr*32 + ty*4;
          *(float4*)(dbase + (size_t)j*N_ + i0) =
            make_float4(o[rr*4+0][cc*4+c], o[rr*4+1][cc*4+c], o[rr*4+2][cc*4+c], o[rr*4+3][cc*4+c]);
        }
      }
  }
}

// ---------------- projection GEMM: Y = X @ W^T (+bias), 64x64 tiles, pipelined ----------------
__global__ __launch_bounds__(64, 2) void k_gemm3(const float* __restrict__ X,
    const float* __restrict__ W0, const float* __restrict__ W1, const float* __restrict__ W2,
    const float* __restrict__ bias,
    float* __restrict__ Y0, float* __restrict__ Y1, float* __restrict__ Y2){
  const float* W = (blockIdx.z==0)?W0:(blockIdx.z==1)?W1:W2;
  float* Y = (blockIdx.z==0)?Y0:(blockIdx.z==1)?Y1:Y2;
  int bi = blockIdx.y, bj = blockIdx.x;
  const float* pa = X + (size_t)(bi*64)*C_;
  const float* pb = W + (size_t)(bj*64)*C_;
  __shared__ float As[16][68];
  __shared__ float Bs[16][68];
  int t = threadIdx.x;
  int tx = t & 7, ty = t >> 3;
  float acc[8][8] = {};
  KLOOP_PIPE
  float bs[8];
  #pragma unroll
  for (int cc=0;cc<2;cc++)
    #pragma unroll
    for (int c=0;c<4;c++) bs[cc*4+c] = bias ? bias[bj*64 + cc*32 + tx*4 + c] : 0.f;
  #pragma unroll
  for (int rr=0;rr<2;rr++)
    #pragma unroll
    for (int r=0;r<4;r++){
      int m = bi*64 + rr*32 + ty*4 + r;
      #pragma unroll
      for (int cc=0;cc<2;cc++){
        int j0 = bj*64 + cc*32 + tx*4;
        *(float4*)(Y + (size_t)m*C_ + j0) =
          make_float4(acc[rr*4+r][cc*4+0]+bs[cc*4+0], acc[rr*4+r][cc*4+1]+bs[cc*4+1],
                      acc[rr*4+r][cc*4+2]+bs[cc*4+2], acc[rr*4+r][cc*4+3]+bs[cc*4+3]);
      }
    }
}

// ---------------- per-row 5 smallest -> density (+noise), row max ----------------
__global__ __launch_bounds__(256) void k_top5(const float* __restrict__ dist, float* __restrict__ density,
                                              float* __restrict__ rowmax){
  int row = blockIdx.x * 4 + (threadIdx.x >> 6);
  int l = threadIdx.x & 63;
  const float* p = dist + (size_t)row * N_;
  float t[5] = {1e30f,1e30f,1e30f,1e30f,1e30f};
  float mx = 0.f;
  #pragma unroll
  for (int q2=0;q2<16;q2++){
    float v = p[l + 64*q2];
    mx = fmaxf(mx, v);
    if (v < t[4]){
      t[4] = v;
      #pragma unroll
      for (int a=4;a>0;a--) if (t[a] < t[a-1]) { float tmp=t[a]; t[a]=t[a-1]; t[a-1]=tmp; }
    }
  }
  #pragma unroll
  for (int m=32;m;m>>=1) mx = fmaxf(mx, __shfl_xor(mx, m));
  float sumsq = 0.f;
  int hi = 0;
  #pragma unroll
  for (int a=0;a<5;a++){
    float head = (hi==0)?t[0]:(hi==1)?t[1]:(hi==2)?t[2]:(hi==3)?t[3]:(hi==4)?t[4]:1e30f;
    float m = head;
    #pragma unroll
    for (int mm=32;mm;mm>>=1) m = fminf(m, __shfl_xor(m, mm));
    sumsq += m*m;
    unsigned long long ball = __ballot(head == m);
    if (l == (__ffsll(ball) - 1)) hi++;
  }
  if (l == 0){
    float msq = sumsq / 5.0f;
    density[row] = expf(-msq) + tf_noise((unsigned)row) * 1e-6f;
    rowmax[row] = mx;
  }
}

__global__ __launch_bounds__(256) void k_bmax(const float* __restrict__ rowmax, float* __restrict__ bmax){
  int b = blockIdx.x; int t = threadIdx.x;
  float m = fmaxf(fmaxf(rowmax[b*N_+t], rowmax[b*N_+t+256]),
                  fmaxf(rowmax[b*N_+t+512], rowmax[b*N_+t+768]));
  __shared__ float s[256];
  s[t]=m; __syncthreads();
  for (int d=128; d; d>>=1){ if (t<d) s[t]=fmaxf(s[t],s[t+d]); __syncthreads(); }
  if (t==0) bmax[b]=s[0];
}

// ---------------- d_ind = min dist over higher-density peers; score ----------------
__global__ __launch_bounds__(256) void k_dind(const float* __restrict__ dist, const float* __restrict__ density,
                                              const float* __restrict__ bmax, float* __restrict__ score){
  int row = blockIdx.x * 4 + (threadIdx.x >> 6);
  int b = row >> 10;
  int l = threadIdx.x & 63;
  const float* p = dist + (size_t)row * N_;
  const float* db = density + b*N_;
  float di = density[row];
  float m = bmax[b];
  #pragma unroll
  for (int q2=0;q2<16;q2++){
    int j = l + 64*q2;
    float dj = db[j];
    if (dj > di) m = fminf(m, p[j]);
  }
  #pragma unroll
  for (int mm=32;mm;mm>>=1) m = fminf(m, __shfl_xor(m, mm));
  if (l==0) score[row] = m * di;
}

// ---------------- stable top-256: bitonic with shuffle strides (j<=32) ----------------
__global__ __launch_bounds__(1024) void k_top256(const float* __restrict__ score, int* __restrict__ idxdown){
  int b = blockIdx.x; int t = threadIdx.x;
  __shared__ float sv[1024];
  __shared__ int si[1024];
  float v = score[b*N_ + t];
  int i = t;
  for (int k = 2; k <= 1024; k <<= 1){
    for (int j = k >> 1; j > 0; j >>= 1){
      float v2; int i2;
      if (j >= 64){
        sv[t] = v; si[t] = i;
        __syncthreads();
        v2 = sv[t ^ j]; i2 = si[t ^ j];
        __syncthreads();
      } else {
        v2 = __shfl_xor(v, j);
        i2 = __shfl_xor(i, j);
      }
      bool islo = (t & j) == 0;
      float lov = islo ? v : v2,  hiv = islo ? v2 : v;
      int   loi = islo ? i : i2,  hii = islo ? i2 : i;
      bool prec = (lov > hiv) || (lov == hiv && loi < hii); // lower-pos elem precedes
      bool up = ((t & k) == 0);
      bool dosw = up ? !prec : prec;
      if (dosw){ v = v2; i = i2; }
    }
  }
  if (t < CN_) idxdown[b*CN_ + t] = i;
}

// ---------------- assign: 4 center-chunks x 64 tokens, first-occurrence argmin ----------------
__global__ __launch_bounds__(256) void k_assign(const float* __restrict__ dist, const int* __restrict__ idxdown,
                                                int* __restrict__ idxclu){
  int b = blockIdx.y;
  int l = threadIdx.x & 63;
  int ch = threadIdx.x >> 6;
  int j = blockIdx.x*64 + l;
  __shared__ int cen[256];
  __shared__ float sd[4][64];
  __shared__ int sk[4][64];
  cen[threadIdx.x] = idxdown[b*CN_ + threadIdx.x];
  __syncthreads();
  const float* dbase = dist + (size_t)b*N_*N_;
  float best = 1e30f; int bk = 0;
  #pragma unroll 8
  for (int kk=0; kk<64; kk++){
    int k = ch*64 + kk;
    float d = dbase[(size_t)cen[k]*N_ + j];
    if (d < best){ best = d; bk = k; }
  }
  sd[ch][l] = best; sk[ch][l] = bk;
  __syncthreads();
  if (ch == 0){
    #pragma unroll
    for (int c2=1;c2<4;c2++){
      float d = sd[c2][l];
      if (d < best){ best = d; bk = sk[c2][l]; }
    }
    idxclu[b*N_ + j] = bk;
  }
}

__global__ void k_setcenters(const int* __restrict__ idxdown, int* __restrict__ idxclu){
  int b = blockIdx.x; int t = threadIdx.x;
  idxclu[b*N_ + idxdown[b*CN_ + t]] = t;
}

// ---------------- hist + scan + scatter in one LDS-resident kernel ----------------
__global__ __launch_bounds__(256) void k_build(const int* __restrict__ idxclu, int* __restrict__ off,
                                               int* __restrict__ cnt, int* __restrict__ members){
  int b = blockIdx.x; int t = threadIdx.x;
  __shared__ int sc[256], so[256];
  sc[t] = 0;
  __syncthreads();
  int cl[4];
  #pragma unroll
  for (int i=0;i<4;i++){
    cl[i] = idxclu[b*N_ + i*256 + t];
    atomicAdd(&sc[cl[i]], 1);
  }
  __syncthreads();
  int mine = sc[t];
  so[t] = mine;
  __syncthreads();
  for (int d=1; d<256; d<<=1){
    int v2 = 0;
    if (t>=d) v2 = so[t-d];
    __syncthreads();
    if (t>=d) so[t] += v2;
    __syncthreads();
  }
  int excl = so[t] - mine;
  off[b*CN_+t] = excl;
  cnt[b*CN_+t] = mine;
  sc[t] = excl;
  __syncthreads();
  #pragma unroll
  for (int i=0;i<4;i++){
    int p = atomicAdd(&sc[cl[i]], 1);
    members[b*N_ + p] = i*256 + t;
  }
}

// ---------------- vsum: two-phase parallel ----------------
__global__ __launch_bounds__(256) void k_vsum1(const float* __restrict__ v, float* __restrict__ vsp){
  int p = blockIdx.x;
  int b = p >> 4, s = p & 15;
  int c = threadIdx.x;
  float acc = 0.f;
  const float* base = v + ((size_t)b*N_ + s*64)*C_ + c;
  #pragma unroll 8
  for (int i=0;i<64;i++) acc += base[(size_t)i*C_];
  vsp[(size_t)p*C_ + c] = acc;
}

__global__ __launch_bounds__(256) void k_vsum2(const float* __restrict__ vsp, float* __restrict__ vsum){
  int b = blockIdx.x; int c = threadIdx.x;
  float s = 0.f;
  #pragma unroll
  for (int i=0;i<16;i++) s += vsp[((size_t)b*16 + i)*C_ + c];
  vsum[b*C_ + c] = s;
}

// ---------------- cluster-sparse attention ----------------
__global__ __launch_bounds__(256) void k_attn(const float* __restrict__ q, const float* __restrict__ kmat,
                                              const float* __restrict__ v, const float* __restrict__ vsum,
                                              const int* __restrict__ idxclu, const int* __restrict__ off,
                                              const int* __restrict__ cnt, const int* __restrict__ members,
                                              float* __restrict__ att){
  int bi = blockIdx.x;
  int b = bi >> 10;
  int h = threadIdx.x >> 6, l = threadIdx.x & 63;
  int c = idxclu[bi];
  int o = off[b*CN_ + c], m = cnt[b*CN_ + c];
  int ch = h*64 + l;
  float qv = q[(size_t)bi*C_ + ch];
  float acc = 0.f, den = 0.f;
  const int* mem = members + b*N_ + o;
  for (int t=0;t<m;t++){
    int j = mem[t];
    size_t base = ((size_t)(b*N_ + j))*C_ + ch;
    float p = qv * kmat[base];
    #pragma unroll
    for (int mm=32;mm;mm>>=1) p += __shfl_xor(p, mm);
    float s = p * 0.125f;
    float e = (s == 0.0f) ? 0.0f : expf(s);
    den += e;
    acc += e * v[base];
  }
  float outv = (acc + (EPS_/1024.0f) * vsum[b*C_ + ch]) / (den + EPS_);
  att[(size_t)bi*C_ + ch] = outv;
}

extern "C" void kernel_launch(void* const* d_in, const int* in_sizes, int n_in,
                              void* d_out, int out_size, void* d_ws, size_t ws_size,
                              hipStream_t stream){
  const float* x  = (const float*)d_in[0];
  const float* Wq = (const float*)d_in[1];
  const float* Wk = (const float*)d_in[2];
  const float* Wv = (const float*)d_in[3];
  const float* Wp = (const float*)d_in[4];
  const float* bp = (const float*)d_in[5];
  float* out = (float*)d_out;

  float* ws = (float*)d_ws;
  float* dist    = ws;
  float* q       = dist + (size_t)B_*N_*N_;
  float* kk      = q    + (size_t)B_*N_*C_;
  float* v       = kk   + (size_t)B_*N_*C_;
  float* att     = v    + (size_t)B_*N_*C_;
  float* vsp     = att  + (size_t)B_*N_*C_;
  float* vsum    = vsp + 128*C_;
  float* sq      = vsum + B_*C_;
  float* rowmax  = sq + B_*N_;
  float* bmax    = rowmax + B_*N_;
  float* density = bmax + 16;
  float* score   = density + B_*N_;
  int* idxdown   = (int*)(score + B_*N_);
  int* idxclu    = idxdown + B_*CN_;
  int* cnt       = idxclu + B_*N_;
  int* off       = cnt + B_*CN_;
  int* members   = off + B_*CN_;

  k_sq<<<B_*N_/4,256,0,stream>>>(x, sq);
  k_dist3<<<dim3(136,8),64,0,stream>>>(x, sq, dist);
  k_top5<<<B_*N_/4,256,0,stream>>>(dist, density, rowmax);
  k_bmax<<<8,256,0,stream>>>(rowmax, bmax);
  k_dind<<<B_*N_/4,256,0,stream>>>(dist, density, bmax, score);
  k_top256<<<8,1024,0,stream>>>(score, idxdown);
  k_assign<<<dim3(16,8),256,0,stream>>>(dist, idxdown, idxclu);
  k_setcenters<<<8,256,0,stream>>>(idxdown, idxclu);
  k_build<<<8,256,0,stream>>>(idxclu, off, cnt, members);
  k_gemm3<<<dim3(4,128,3),64,0,stream>>>(x, Wq, Wk, Wv, nullptr, q, kk, v);
  k_vsum1<<<128,256,0,stream>>>(v, vsp);
  k_vsum2<<<8,256,0,stream>>>(vsp, vsum);
  k_attn<<<B_*N_,256,0,stream>>>(q, kk, v, vsum, idxclu, off, cnt, members, att);
  k_gemm3<<<dim3(4,128,1),64,0,stream>>>(att, Wp, Wp, Wp, bp, out, out, out);
}

// Round 6
// 302.714 us; speedup vs baseline: 2.3548x; 2.3548x over previous
//
#include <hip/hip_runtime.h>
#include <math.h>

#define B_ 8
#define N_ 1024
#define C_ 256
#define H_ 4
#define D_ 64
#define CN_ 256
#define EPS_ 1e-6f

// ---------------- threefry2x32 (JAX-compatible) ----------------
__device__ __forceinline__ unsigned rotl32(unsigned x, int r){ return (x<<r)|(x>>(32-r)); }

__device__ float tf_noise(unsigned gid){
  unsigned c0 = (gid >= 4096u) ? gid - 4096u : gid;
  unsigned c1 = c0 + 4096u;
  const unsigned k0 = 0u, k1 = 42u;
  const unsigned ks2 = k0 ^ k1 ^ 0x1BD11BDAu;
  unsigned x0 = c0 + k0, x1 = c1 + k1;
  const int R0[4] = {13,15,26,6};
  const int R1[4] = {17,29,16,24};
  #pragma unroll
  for (int i=0;i<4;i++){ x0 += x1; x1 = rotl32(x1,R0[i]); x1 ^= x0; }
  x0 += k1; x1 += ks2 + 1u;
  #pragma unroll
  for (int i=0;i<4;i++){ x0 += x1; x1 = rotl32(x1,R1[i]); x1 ^= x0; }
  x0 += ks2; x1 += k0 + 2u;
  #pragma unroll
  for (int i=0;i<4;i++){ x0 += x1; x1 = rotl32(x1,R0[i]); x1 ^= x0; }
  x0 += k0; x1 += k1 + 3u;
  #pragma unroll
  for (int i=0;i<4;i++){ x0 += x1; x1 = rotl32(x1,R1[i]); x1 ^= x0; }
  x0 += k1; x1 += ks2 + 4u;
  #pragma unroll
  for (int i=0;i<4;i++){ x0 += x1; x1 = rotl32(x1,R0[i]); x1 ^= x0; }
  x0 += ks2; x1 += k0 + 5u;
  unsigned bits = (gid >= 4096u) ? x1 : x0;
  return __uint_as_float(0x3F800000u | (bits >> 9)) - 1.0f;
}

// ---------------- sq of rows ----------------
__global__ __launch_bounds__(256) void k_sq(const float* __restrict__ x, float* __restrict__ sq){
  int row = blockIdx.x * 4 + (threadIdx.x >> 6);
  int l = threadIdx.x & 63;
  const float* p = x + (size_t)row * C_;
  float s = 0.f;
  #pragma unroll
  for (int t=0;t<4;t++){ float v = p[l + 64*t]; s += v*v; }
  #pragma unroll
  for (int m=32;m;m>>=1) s += __shfl_xor(s, m);
  if (l==0) sq[row] = s;
}

// ---------------- dist GEMM: 128x128 tile, BK=32, 8x8 micro, 256 thr ----------------
__global__ __launch_bounds__(256) void k_dist4(const float* __restrict__ x, const float* __restrict__ sq,
                                               float* __restrict__ dist){
  int b = blockIdx.z, bi = blockIdx.y, bj = blockIdx.x;
  const float* xb = x + (size_t)b*N_*C_;
  const float* pa = xb + (size_t)(bi*128)*C_;
  const float* pb = xb + (size_t)(bj*128)*C_;
  __shared__ float As[32][132];
  __shared__ float Bs[32][132];
  int tid = threadIdx.x;
  int tx = tid & 15, ty = tid >> 4;
  float acc[8][8] = {};
  for (int k0=0;k0<C_;k0+=32){
    #pragma unroll
    for (int f=0; f<4; f++){
      int e = f*256 + tid; int row = e>>3, kq = e&7;
      float4 a = *(const float4*)(pa + (size_t)row*C_ + k0 + kq*4);
      float4 c = *(const float4*)(pb + (size_t)row*C_ + k0 + kq*4);
      As[kq*4+0][row]=a.x; As[kq*4+1][row]=a.y; As[kq*4+2][row]=a.z; As[kq*4+3][row]=a.w;
      Bs[kq*4+0][row]=c.x; Bs[kq*4+1][row]=c.y; Bs[kq*4+2][row]=c.z; Bs[kq*4+3][row]=c.w;
    }
    __syncthreads();
    #pragma unroll
    for (int kk=0;kk<32;kk++){
      float4 a0 = *(const float4*)&As[kk][ty*4];
      float4 a1 = *(const float4*)&As[kk][64+ty*4];
      float4 b0 = *(const float4*)&Bs[kk][tx*4];
      float4 b1 = *(const float4*)&Bs[kk][64+tx*4];
      float av[8]={a0.x,a0.y,a0.z,a0.w,a1.x,a1.y,a1.z,a1.w};
      float bv[8]={b0.x,b0.y,b0.z,b0.w,b1.x,b1.y,b1.z,b1.w};
      #pragma unroll
      for (int r=0;r<8;r++)
        #pragma unroll
        for (int c=0;c<8;c++) acc[r][c] += av[r]*bv[c];
    }
    __syncthreads();
  }
  float sqj[8];
  #pragma unroll
  for (int cc=0;cc<2;cc++)
    #pragma unroll
    for (int c=0;c<4;c++) sqj[cc*4+c] = sq[b*N_ + bj*128 + cc*64 + tx*4 + c];
  float* dbase = dist + (size_t)b*N_*N_;
  #pragma unroll
  for (int rr=0;rr<2;rr++){
    #pragma unroll
    for (int r=0;r<4;r++){
      int i = bi*128 + rr*64 + ty*4 + r;
      float si = sq[b*N_ + i];
      #pragma unroll
      for (int cc=0;cc<2;cc++){
        int j0 = bj*128 + cc*64 + tx*4;
        float o[4];
        #pragma unroll
        for (int c=0;c<4;c++){
          float d2 = si + sqj[cc*4+c] - 2.f*acc[rr*4+r][cc*4+c];
          o[c] = sqrtf(fmaxf(d2, 0.f)) * 0.0625f;
        }
        *(float4*)(dbase + (size_t)i*N_ + j0) = make_float4(o[0],o[1],o[2],o[3]);
      }
    }
  }
}

// ---------------- projection GEMM: Y = X @ W^T (+bias), 128x64 tile, BK=32 ----------------
__global__ __launch_bounds__(256) void k_proj(const float* __restrict__ X,
    const float* __restrict__ W0, const float* __restrict__ W1, const float* __restrict__ W2,
    const float* __restrict__ bias,
    float* __restrict__ Y0, float* __restrict__ Y1, float* __restrict__ Y2){
  const float* W = (blockIdx.z==0)?W0:(blockIdx.z==1)?W1:W2;
  float* Y = (blockIdx.z==0)?Y0:(blockIdx.z==1)?Y1:Y2;
  int bi = blockIdx.y, bj = blockIdx.x;
  const float* pa = X + (size_t)(bi*128)*C_;
  const float* pb = W + (size_t)(bj*64)*C_;
  __shared__ float As[32][132];
  __shared__ float Bs[32][68];
  int tid = threadIdx.x;
  int tx = tid & 15, ty = tid >> 4;
  float acc[8][4] = {};
  for (int k0=0;k0<C_;k0+=32){
    #pragma unroll
    for (int f=0; f<4; f++){
      int e = f*256 + tid; int row = e>>3, kq = e&7;
      float4 a = *(const float4*)(pa + (size_t)row*C_ + k0 + kq*4);
      As[kq*4+0][row]=a.x; As[kq*4+1][row]=a.y; As[kq*4+2][row]=a.z; As[kq*4+3][row]=a.w;
    }
    #pragma unroll
    for (int f=0; f<2; f++){
      int e = f*256 + tid; int row = e>>3, kq = e&7;
      float4 c = *(const float4*)(pb + (size_t)row*C_ + k0 + kq*4);
      Bs[kq*4+0][row]=c.x; Bs[kq*4+1][row]=c.y; Bs[kq*4+2][row]=c.z; Bs[kq*4+3][row]=c.w;
    }
    __syncthreads();
    #pragma unroll
    for (int kk=0;kk<32;kk++){
      float4 a0 = *(const float4*)&As[kk][ty*4];
      float4 a1 = *(const float4*)&As[kk][64+ty*4];
      float4 b0 = *(const float4*)&Bs[kk][tx*4];
      float av[8]={a0.x,a0.y,a0.z,a0.w,a1.x,a1.y,a1.z,a1.w};
      float bv[4]={b0.x,b0.y,b0.z,b0.w};
      #pragma unroll
      for (int r=0;r<8;r++)
        #pragma unroll
        for (int c=0;c<4;c++) acc[r][c] += av[r]*bv[c];
    }
    __syncthreads();
  }
  float bs[4];
  #pragma unroll
  for (int c=0;c<4;c++) bs[c] = bias ? bias[bj*64 + tx*4 + c] : 0.f;
  #pragma unroll
  for (int rr=0;rr<2;rr++)
    #pragma unroll
    for (int r=0;r<4;r++){
      int m = bi*128 + rr*64 + ty*4 + r;
      int j0 = bj*64 + tx*4;
      *(float4*)(Y + (size_t)m*C_ + j0) =
        make_float4(acc[rr*4+r][0]+bs[0], acc[rr*4+r][1]+bs[1],
                    acc[rr*4+r][2]+bs[2], acc[rr*4+r][3]+bs[3]);
    }
}

// ---------------- per-row 5 smallest -> density (+noise), row max ----------------
__global__ __launch_bounds__(256) void k_top5(const float* __restrict__ dist, float* __restrict__ density,
                                              float* __restrict__ rowmax){
  int row = blockIdx.x * 4 + (threadIdx.x >> 6);
  int l = threadIdx.x & 63;
  const float* p = dist + (size_t)row * N_;
  float t[5] = {1e30f,1e30f,1e30f,1e30f,1e30f};
  float mx = 0.f;
  #pragma unroll
  for (int q2=0;q2<16;q2++){
    float v = p[l + 64*q2];
    mx = fmaxf(mx, v);
    if (v < t[4]){
      t[4] = v;
      #pragma unroll
      for (int a=4;a>0;a--) if (t[a] < t[a-1]) { float tmp=t[a]; t[a]=t[a-1]; t[a-1]=tmp; }
    }
  }
  #pragma unroll
  for (int m=32;m;m>>=1) mx = fmaxf(mx, __shfl_xor(mx, m));
  float sumsq = 0.f;
  int hi = 0;
  #pragma unroll
  for (int a=0;a<5;a++){
    float head = (hi==0)?t[0]:(hi==1)?t[1]:(hi==2)?t[2]:(hi==3)?t[3]:(hi==4)?t[4]:1e30f;
    float m = head;
    #pragma unroll
    for (int mm=32;mm;mm>>=1) m = fminf(m, __shfl_xor(m, mm));
    sumsq += m*m;
    unsigned long long ball = __ballot(head == m);
    if (l == (__ffsll(ball) - 1)) hi++;
  }
  if (l == 0){
    float msq = sumsq / 5.0f;
    density[row] = expf(-msq) + tf_noise((unsigned)row) * 1e-6f;
    rowmax[row] = mx;
  }
}

__global__ __launch_bounds__(256) void k_bmax(const float* __restrict__ rowmax, float* __restrict__ bmax){
  int b = blockIdx.x; int t = threadIdx.x;
  float m = fmaxf(fmaxf(rowmax[b*N_+t], rowmax[b*N_+t+256]),
                  fmaxf(rowmax[b*N_+t+512], rowmax[b*N_+t+768]));
  __shared__ float s[256];
  s[t]=m; __syncthreads();
  for (int d=128; d; d>>=1){ if (t<d) s[t]=fmaxf(s[t],s[t+d]); __syncthreads(); }
  if (t==0) bmax[b]=s[0];
}

// ---------------- d_ind = min dist over higher-density peers; score ----------------
__global__ __launch_bounds__(256) void k_dind(const float* __restrict__ dist, const float* __restrict__ density,
                                              const float* __restrict__ bmax, float* __restrict__ score){
  int row = blockIdx.x * 4 + (threadIdx.x >> 6);
  int b = row >> 10;
  int l = threadIdx.x & 63;
  const float* p = dist + (size_t)row * N_;
  const float* db = density + b*N_;
  float di = density[row];
  float m = bmax[b];
  #pragma unroll
  for (int q2=0;q2<16;q2++){
    int j = l + 64*q2;
    float dj = db[j];
    if (dj > di) m = fminf(m, p[j]);
  }
  #pragma unroll
  for (int mm=32;mm;mm>>=1) m = fminf(m, __shfl_xor(m, mm));
  if (l==0) score[row] = m * di;
}

// ---------------- stable top-256: bitonic with shuffle strides (j<=32) ----------------
__global__ __launch_bounds__(1024) void k_top256(const float* __restrict__ score, int* __restrict__ idxdown){
  int b = blockIdx.x; int t = threadIdx.x;
  __shared__ float sv[1024];
  __shared__ int si[1024];
  float v = score[b*N_ + t];
  int i = t;
  for (int k = 2; k <= 1024; k <<= 1){
    for (int j = k >> 1; j > 0; j >>= 1){
      float v2; int i2;
      if (j >= 64){
        sv[t] = v; si[t] = i;
        __syncthreads();
        v2 = sv[t ^ j]; i2 = si[t ^ j];
        __syncthreads();
      } else {
        v2 = __shfl_xor(v, j);
        i2 = __shfl_xor(i, j);
      }
      bool islo = (t & j) == 0;
      float lov = islo ? v : v2,  hiv = islo ? v2 : v;
      int   loi = islo ? i : i2,  hii = islo ? i2 : i;
      bool prec = (lov > hiv) || (lov == hiv && loi < hii);
      bool up = ((t & k) == 0);
      bool dosw = up ? !prec : prec;
      if (dosw){ v = v2; i = i2; }
    }
  }
  if (t < CN_) idxdown[b*CN_ + t] = i;
}

// ---------------- assign: 4 center-chunks x 64 tokens, first-occurrence argmin ----------------
__global__ __launch_bounds__(256) void k_assign(const float* __restrict__ dist, const int* __restrict__ idxdown,
                                                int* __restrict__ idxclu){
  int b = blockIdx.y;
  int l = threadIdx.x & 63;
  int ch = threadIdx.x >> 6;
  int j = blockIdx.x*64 + l;
  __shared__ int cen[256];
  __shared__ float sd[4][64];
  __shared__ int sk[4][64];
  cen[threadIdx.x] = idxdown[b*CN_ + threadIdx.x];
  __syncthreads();
  const float* dbase = dist + (size_t)b*N_*N_;
  float best = 1e30f; int bk = 0;
  #pragma unroll 8
  for (int kk=0; kk<64; kk++){
    int k = ch*64 + kk;
    float d = dbase[(size_t)cen[k]*N_ + j];
    if (d < best){ best = d; bk = k; }
  }
  sd[ch][l] = best; sk[ch][l] = bk;
  __syncthreads();
  if (ch == 0){
    #pragma unroll
    for (int c2=1;c2<4;c2++){
      float d = sd[c2][l];
      if (d < best){ best = d; bk = sk[c2][l]; }
    }
    idxclu[b*N_ + j] = bk;
  }
}

__global__ void k_setcenters(const int* __restrict__ idxdown, int* __restrict__ idxclu){
  int b = blockIdx.x; int t = threadIdx.x;
  idxclu[b*N_ + idxdown[b*CN_ + t]] = t;
}

// ---------------- hist + scan + scatter in one LDS-resident kernel ----------------
__global__ __launch_bounds__(256) void k_build(const int* __restrict__ idxclu, int* __restrict__ off,
                                               int* __restrict__ cnt, int* __restrict__ members){
  int b = blockIdx.x; int t = threadIdx.x;
  __shared__ int sc[256], so[256];
  sc[t] = 0;
  __syncthreads();
  int cl[4];
  #pragma unroll
  for (int i=0;i<4;i++){
    cl[i] = idxclu[b*N_ + i*256 + t];
    atomicAdd(&sc[cl[i]], 1);
  }
  __syncthreads();
  int mine = sc[t];
  so[t] = mine;
  __syncthreads();
  for (int d=1; d<256; d<<=1){
    int v2 = 0;
    if (t>=d) v2 = so[t-d];
    __syncthreads();
    if (t>=d) so[t] += v2;
    __syncthreads();
  }
  int excl = so[t] - mine;
  off[b*CN_+t] = excl;
  cnt[b*CN_+t] = mine;
  sc[t] = excl;
  __syncthreads();
  #pragma unroll
  for (int i=0;i<4;i++){
    int p = atomicAdd(&sc[cl[i]], 1);
    members[b*N_ + p] = i*256 + t;
  }
}

// ---------------- vsum: two-phase parallel ----------------
__global__ __launch_bounds__(256) void k_vsum1(const float* __restrict__ v, float* __restrict__ vsp){
  int p = blockIdx.x;
  int b = p >> 4, s = p & 15;
  int c = threadIdx.x;
  float acc = 0.f;
  const float* base = v + ((size_t)b*N_ + s*64)*C_ + c;
  #pragma unroll 8
  for (int i=0;i<64;i++) acc += base[(size_t)i*C_];
  vsp[(size_t)p*C_ + c] = acc;
}

__global__ __launch_bounds__(256) void k_vsum2(const float* __restrict__ vsp, float* __restrict__ vsum){
  int b = blockIdx.x; int c = threadIdx.x;
  float s = 0.f;
  #pragma unroll
  for (int i=0;i<16;i++) s += vsp[((size_t)b*16 + i)*C_ + c];
  vsum[b*C_ + c] = s;
}

// ---------------- cluster-sparse attention ----------------
__global__ __launch_bounds__(256) void k_attn(const float* __restrict__ q, const float* __restrict__ kmat,
                                              const float* __restrict__ v, const float* __restrict__ vsum,
                                              const int* __restrict__ idxclu, const int* __restrict__ off,
                                              const int* __restrict__ cnt, const int* __restrict__ members,
                                              float* __restrict__ att){
  int bi = blockIdx.x;
  int b = bi >> 10;
  int h = threadIdx.x >> 6, l = threadIdx.x & 63;
  int c = idxclu[bi];
  int o = off[b*CN_ + c], m = cnt[b*CN_ + c];
  int ch = h*64 + l;
  float qv = q[(size_t)bi*C_ + ch];
  float acc = 0.f, den = 0.f;
  const int* mem = members + b*N_ + o;
  for (int t=0;t<m;t++){
    int j = mem[t];
    size_t base = ((size_t)(b*N_ + j))*C_ + ch;
    float p = qv * kmat[base];
    #pragma unroll
    for (int mm=32;mm;mm>>=1) p += __shfl_xor(p, mm);
    float s = p * 0.125f;
    float e = (s == 0.0f) ? 0.0f : expf(s);
    den += e;
    acc += e * v[base];
  }
  float outv = (acc + (EPS_/1024.0f) * vsum[b*C_ + ch]) / (den + EPS_);
  att[(size_t)bi*C_ + ch] = outv;
}

extern "C" void kernel_launch(void* const* d_in, const int* in_sizes, int n_in,
                              void* d_out, int out_size, void* d_ws, size_t ws_size,
                              hipStream_t stream){
  const float* x  = (const float*)d_in[0];
  const float* Wq = (const float*)d_in[1];
  const float* Wk = (const float*)d_in[2];
  const float* Wv = (const float*)d_in[3];
  const float* Wp = (const float*)d_in[4];
  const float* bp = (const float*)d_in[5];
  float* out = (float*)d_out;

  float* ws = (float*)d_ws;
  float* dist    = ws;
  float* q       = dist + (size_t)B_*N_*N_;
  float* kk      = q    + (size_t)B_*N_*C_;
  float* v       = kk   + (size_t)B_*N_*C_;
  float* att     = v    + (size_t)B_*N_*C_;
  float* vsp     = att  + (size_t)B_*N_*C_;
  float* vsum    = vsp + 128*C_;
  float* sq      = vsum + B_*C_;
  float* rowmax  = sq + B_*N_;
  float* bmax    = rowmax + B_*N_;
  float* density = bmax + 16;
  float* score   = density + B_*N_;
  int* idxdown   = (int*)(score + B_*N_);
  int* idxclu    = idxdown + B_*CN_;
  int* cnt       = idxclu + B_*N_;
  int* off       = cnt + B_*CN_;
  int* members   = off + B_*CN_;

  k_sq<<<B_*N_/4,256,0,stream>>>(x, sq);
  k_dist4<<<dim3(8,8,8),256,0,stream>>>(x, sq, dist);
  k_top5<<<B_*N_/4,256,0,stream>>>(dist, density, rowmax);
  k_bmax<<<8,256,0,stream>>>(rowmax, bmax);
  k_dind<<<B_*N_/4,256,0,stream>>>(dist, density, bmax, score);
  k_top256<<<8,1024,0,stream>>>(score, idxdown);
  k_assign<<<dim3(16,8),256,0,stream>>>(dist, idxdown, idxclu);
  k_setcenters<<<8,256,0,stream>>>(idxdown, idxclu);
  k_build<<<8,256,0,stream>>>(idxclu, off, cnt, members);
  k_proj<<<dim3(4,64,3),256,0,stream>>>(x, Wq, Wk, Wv, nullptr, q, kk, v);
  k_vsum1<<<128,256,0,stream>>>(v, vsp);
  k_vsum2<<<8,256,0,stream>>>(vsp, vsum);
  k_attn<<<B_*N_,256,0,stream>>>(q, kk, v, vsum, idxclu, off, cnt, members, att);
  k_proj<<<dim3(4,64,1),256,0,stream>>>(att, Wp, Wp, Wp, bp, out, out, out);
}